// Round 1
// baseline (32556.351 us; speedup 1.0000x reference)
//
#include <hip/hip_runtime.h>

// ---------------------------------------------------------------------------
// FarGAN wave head: frame MLP + phase gen + 3-layer GRU (pipelined across 9
// persistent workgroups, bf16 MFMA, register-resident weights) + output head.
// ---------------------------------------------------------------------------

#define B_    16
#define T_    50
#define SF_   4
#define SPS_  40
#define S_    8000      // T*SF*SPS
#define TS_   200       // T*SF
#define DIN_  48
#define PED_  64
#define COND_ 128
#define GRUD_ 192
#define G3_   576
#define GRUIN_ 194
#define TWO_PI_F 6.2831853071795864769f

// workspace byte offsets (all 256-aligned)
#define OFF_FLAGS 0          //  9 ints: per-block publish step counter
#define OFF_PROG  256        //  9 ints: per-block consume progress
#define OFF_DV    1024       // 16*50 f32
#define OFF_V     8192       // 16*50 f32
#define OFF_SIN   32768      // 8000*16 f32  sin[t][b]
#define OFF_COS   557056     // 8000*16 f32
#define OFF_PE    1081344    // 16*50*64 f32
#define OFF_COND  1310720    // 16*200*128 f32
#define OFF_GB    2949120    // gbase: 200*36*64*4 f32 (D-tile layout)
#define OFF_WF    10321920   // wfrag: 5*36*6*64*8 bf16 (B-frag layout)
#define OFF_FRAG  11427840   // fragbuf: 3*64*6*64*8 bf16 (A-frag ring)
#define OFF_PART  12607488   // part: 3*16*8000 f32
// end ~ 14.14 MB

typedef short s16x8 __attribute__((ext_vector_type(8)));
typedef float f32x4 __attribute__((ext_vector_type(4)));

__device__ __forceinline__ short f2bf(float f) {
  unsigned u = __float_as_uint(f);
  unsigned r = (u + 0x7FFFu + ((u >> 16) & 1u)) >> 16;   // RNE
  return (short)r;
}
__device__ __forceinline__ float sigm(float x) {
  return __fdividef(1.f, 1.f + __expf(-x));
}
__device__ __forceinline__ float tanhx(float x) {
  float e = __expf(2.f * x);
  return __fdividef(e - 1.f, e + 1.f);
}

// ---------------------------------------------------------------------------
// K1: per-(b,t) frame processing: period/idx/v/delta, pe lookup, 2-layer MLP
// ---------------------------------------------------------------------------
__global__ void k_frame(const float* __restrict__ feats,
                        const float* __restrict__ pembed,
                        const float* __restrict__ w1, const float* __restrict__ b1,
                        const float* __restrict__ w2, const float* __restrict__ b2,
                        char* ws) {
  const int bt = blockIdx.x;            // b*50 + t
  const int tid = threadIdx.x;          // 128 threads
  float* dvp = (float*)(ws + OFF_DV);
  float* vp  = (float*)(ws + OFF_V);
  float* pep = (float*)(ws + OFF_PE);
  float* cnd = (float*)(ws + OFF_COND);

  __shared__ float fin[112];
  __shared__ float h1[256];
  __shared__ int   sidx;

  if (tid == 0) {
    float f0 = feats[bt * 48 + 46];
    float vo = feats[bt * 48 + 47];
    float period = fminf(fmaxf(256.f * exp2f(-(f0 + 2.f)), 32.f), 255.f);
    int idx = (int)rintf(period) - 32;             // jnp.round = RNE
    float f0hz = 16000.f / fmaxf(period, 1.f);
    float v = fminf(fmaxf(vo, 0.f), 1.f);
    float delta = TWO_PI_F * fmaxf(f0hz, 60.f) * (1.f / 16000.f);
    dvp[bt] = delta * v;
    vp[bt] = v;
    sidx = idx;
  }
  __syncthreads();
  if (tid < 48) fin[tid] = feats[bt * 48 + tid];
  if (tid < 64) {
    float pv = pembed[sidx * 64 + tid];
    fin[48 + tid] = pv;
    pep[bt * 64 + tid] = pv;
  }
  __syncthreads();
  #pragma unroll
  for (int rr = 0; rr < 2; ++rr) {
    int r = tid + rr * 128;
    const float* wr = w1 + r * 112;
    float acc = b1[r];
    #pragma unroll 4
    for (int k = 0; k < 112; ++k) acc += wr[k] * fin[k];
    // exact gelu
    h1[r] = 0.5f * acc * (1.f + erff(acc * 0.70710678118654752440f));
  }
  __syncthreads();
  const int b = bt / 50, t = bt - b * 50;
  #pragma unroll
  for (int rr = 0; rr < 4; ++rr) {
    int r = tid + rr * 128;
    const float* wr = w2 + r * 256;
    float acc = b2[r];
    #pragma unroll 4
    for (int k = 0; k < 256; ++k) acc += wr[k] * h1[k];
    int sf = r >> 7, c = r & 127;
    cnd[((b * 200) + (t * 4 + sf)) * 128 + c] = acc;
  }
}

// ---------------------------------------------------------------------------
// K2: phase cumsum + sin/cos tables  (one block per batch element)
// ---------------------------------------------------------------------------
__global__ void k_phase(char* ws) {
  const int b = blockIdx.x;
  const int tid = threadIdx.x;          // 256
  const float* dvp = (const float*)(ws + OFF_DV);
  float* sinA = (float*)(ws + OFF_SIN);
  float* cosA = (float*)(ws + OFF_COS);

  __shared__ float ps[200];
  __shared__ float dvs[200];
  if (tid == 0) {
    float c = 0.f;
    for (int ts = 0; ts < 200; ++ts) {
      float d = dvp[b * 50 + (ts >> 2)];
      dvs[ts] = d;
      float inc = d * (float)SPS_;
      c = c + inc;                        // inclusive cumsum (match ref order)
      ps[ts] = fmodf(c - inc, TWO_PI_F);
    }
  }
  __syncthreads();
  for (int i = tid; i < S_; i += 256) {
    int ts = i / 40, k = i - ts * 40;
    float ph = ps[ts] + dvs[ts] * (float)k;
    sinA[(size_t)i * 16 + b] = sinf(ph);
    cosA[(size_t)i * 16 + b] = cosf(ph);
  }
}

// ---------------------------------------------------------------------------
// K3: gbase[ts][nt][lane][j] = b_ih0 + Wc@cond + Wp@pe, in MFMA D-tile layout
// ---------------------------------------------------------------------------
__global__ void k_gbase(const float* __restrict__ wih0,
                        const float* __restrict__ bih0, char* ws) {
  const int ts = blockIdx.x;            // 200 blocks, 256 threads
  const int t = ts >> 2;
  const int tid = threadIdx.x;
  const float* cnd = (const float*)(ws + OFF_COND);
  const float* pep = (const float*)(ws + OFF_PE);
  float* gbp = (float*)(ws + OFF_GB);

  __shared__ float c_s[16][128];
  __shared__ float p_s[16][64];
  for (int i = tid; i < 2048; i += 256) c_s[i >> 7][i & 127] = cnd[((i >> 7) * 200 + ts) * 128 + (i & 127)];
  for (int i = tid; i < 1024; i += 256) p_s[i >> 6][i & 63] = pep[((i >> 6) * 50 + t) * 64 + (i & 63)];
  __syncthreads();

  for (int i = tid; i < 9216; i += 256) {
    int row = i >> 4, b = i & 15;
    const float* wr = wih0 + (size_t)row * GRUIN_;
    float acc = bih0[row];
    #pragma unroll 4
    for (int k = 0; k < 128; ++k) acc += wr[k] * c_s[b][k];
    #pragma unroll 4
    for (int k = 0; k < 64; ++k) acc += wr[128 + k] * p_s[b][k];
    int nt = row >> 4, l15 = row & 15;
    int lane = l15 | ((b >> 2) << 4), j = b & 3;
    gbp[((size_t)(ts * 36 + nt) * 64 + lane) * 4 + j] = acc;
  }
}

// ---------------------------------------------------------------------------
// K_w: pack the 5 recurrent weight matrices (576x192) into bf16 B-fragments.
// k-map: k = kt*32 + 16*(e>>2) + 4*(lane>>4) + (e&3)  (same map used when
// packing A-fragments at publish time -> consistent regardless of HW k order)
// ---------------------------------------------------------------------------
__global__ void k_wprep(const float* __restrict__ whh0, const float* __restrict__ wih1,
                        const float* __restrict__ whh1, const float* __restrict__ wih2,
                        const float* __restrict__ whh2, char* ws) {
  const int blk = blockIdx.x;           // 5*36*6 = 1080 blocks, 64 threads
  const int mat = blk / 216, rem = blk - mat * 216;
  const int nt = rem / 6, kt = rem - nt * 6;
  const int lane = threadIdx.x;
  const float* W = (mat == 0) ? whh0 : (mat == 1) ? wih1 : (mat == 2) ? whh1
                  : (mat == 3) ? wih2 : whh2;
  short* dst = (short*)(ws + OFF_WF) + ((size_t)(mat * 36 + nt) * 6 + kt) * 512 + lane * 8;
  const int row = nt * 16 + (lane & 15);
  const int g = lane >> 4;
  #pragma unroll
  for (int e = 0; e < 8; ++e) {
    int k = kt * 32 + 16 * (e >> 2) + 4 * g + (e & 3);
    dst[e] = f2bf(W[(size_t)row * 192 + k]);
  }
}

// ---------------------------------------------------------------------------
// K4: persistent pipelined GRU. 9 blocks = 3 layers x 3 unit-slices.
// Each block: 256 threads = 4 waves; wave w owns 16 GRU units; weights live
// in VGPRs as bf16 MFMA fragments; h handoff via L2 ring + agent atomics.
// ---------------------------------------------------------------------------
__global__ __launch_bounds__(256, 1)
void k_gru(char* ws, const float* __restrict__ wih0,
           const float* __restrict__ bih0, const float* __restrict__ bhh0,
           const float* __restrict__ bih1, const float* __restrict__ bhh1,
           const float* __restrict__ bih2, const float* __restrict__ bhh2,
           const float* __restrict__ outw) {
  const int blk = blockIdx.x;
  const int layer = blk / 3, sl = blk - layer * 3;
  const int tid = threadIdx.x;
  const int w = tid >> 6, lane = tid & 63, lg = lane >> 4, l15 = lane & 15;

  int* flags = (int*)(ws + OFF_FLAGS);
  int* prog  = (int*)(ws + OFF_PROG);
  const float* sinA = (const float*)(ws + OFF_SIN);
  const float* cosA = (const float*)(ws + OFF_COS);
  const float* gbp  = (const float*)(ws + OFF_GB);
  const short* wf   = (const short*)(ws + OFF_WF);
  short* frag       = (short*)(ws + OFF_FRAG);
  float* part       = (float*)(ws + OFF_PART);

  __shared__ __align__(16) short hlds[1024];   // 2 ktiles x 64 lanes x 8
  __shared__ float plds[4][16];

  const int u0 = sl * 64 + w * 16;
  const int ntb = sl * 4 + w;
  const int nts[3] = {ntb, 12 + ntb, 24 + ntb};
  const int rowR = u0 + l15, rowZ = 192 + rowR, rowN = 384 + rowR;

  const float* bih; const float* bhh; int matIH, matHH;
  if (layer == 0)      { bih = bih0; bhh = bhh0; matIH = 0; matHH = 0; }
  else if (layer == 1) { bih = bih1; bhh = bhh1; matIH = 1; matHH = 2; }
  else                 { bih = bih2; bhh = bhh2; matIH = 3; matHH = 4; }

  const float bgi0 = bih[rowR], bgi1 = bih[rowZ], bgi2 = bih[rowN];
  const float bgh0 = bhh[rowR], bgh1 = bhh[rowZ], bgh2 = bhh[rowN];

  // register-resident weight fragments
  s16x8 WH[3][6], WI[3][6];
  #pragma unroll
  for (int g = 0; g < 3; ++g) {
    #pragma unroll
    for (int kt = 0; kt < 6; ++kt) {
      WH[g][kt] = *(const s16x8*)(wf + ((size_t)(matHH * 36 + nts[g]) * 6 + kt) * 512 + lane * 8);
      if (layer > 0)
        WI[g][kt] = *(const s16x8*)(wf + ((size_t)(matIH * 36 + nts[g]) * 6 + kt) * 512 + lane * 8);
      else
        WI[g][kt] = (s16x8){0,0,0,0,0,0,0,0};
    }
  }
  float wsn[3] = {0.f,0.f,0.f}, wcs[3] = {0.f,0.f,0.f};
  if (layer == 0) {
    const int rows[3] = {rowR, rowZ, rowN};
    #pragma unroll
    for (int g = 0; g < 3; ++g) {
      wsn[g] = wih0[(size_t)rows[g] * GRUIN_ + 192];
      wcs[g] = wih0[(size_t)rows[g] * GRUIN_ + 193];
    }
  }
  const float ow = (layer == 2) ? outw[u0 + l15] : 0.f;

  f32x4 h = {0.f, 0.f, 0.f, 0.f};
  f32x4 gbr[3]; gbr[0] = h; gbr[1] = h; gbr[2] = h;

  for (int t = 0; t < S_; ++t) {
    const int slot = t & 63, slot1 = (t - 1) & 63;

    // ---- gi base (no flag dependency -> do before spins) ----
    f32x4 agi0, agi1, agi2;
    f32x4 agh0 = {bgh0, bgh0, bgh0, bgh0};
    f32x4 agh1 = {bgh1, bgh1, bgh1, bgh1};
    f32x4 agh2 = {bgh2, bgh2, bgh2, bgh2};
    if (layer == 0) {
      if ((t % SPS_) == 0) {
        int ts = t / SPS_;
        #pragma unroll
        for (int g = 0; g < 3; ++g)
          gbr[g] = *(const f32x4*)(gbp + ((size_t)(ts * 36 + nts[g]) * 64 + lane) * 4);
      }
      f32x4 s4 = *(const f32x4*)(sinA + (size_t)t * 16 + lg * 4);
      f32x4 c4 = *(const f32x4*)(cosA + (size_t)t * 16 + lg * 4);
      agi0 = gbr[0] + s4 * wsn[0] + c4 * wcs[0];
      agi1 = gbr[1] + s4 * wsn[1] + c4 * wcs[1];
      agi2 = gbr[2] + s4 * wsn[2] + c4 * wcs[2];
    } else {
      agi0 = (f32x4){bgi0, bgi0, bgi0, bgi0};
      agi1 = (f32x4){bgi1, bgi1, bgi1, bgi1};
      agi2 = (f32x4){bgi2, bgi2, bgi2, bgi2};
    }

    // ---- coarse back-pressure (ring is 64 slots; keep lead < ~40) ----
    if ((t & 15) == 0 && t >= 48) {
      int need = t - 40;
      #pragma unroll
      for (int ss = 0; ss < 3; ++ss)
        while (__hip_atomic_load(&prog[layer * 3 + ss], __ATOMIC_RELAXED, __HIP_MEMORY_SCOPE_AGENT) < need)
          __builtin_amdgcn_s_sleep(2);
      if (layer < 2) {
        #pragma unroll
        for (int ss = 0; ss < 3; ++ss)
          while (__hip_atomic_load(&prog[(layer + 1) * 3 + ss], __ATOMIC_RELAXED, __HIP_MEMORY_SCOPE_AGENT) < need)
            __builtin_amdgcn_s_sleep(2);
      }
    }

    // ---- spin on producer flags ----
    if (layer > 0) {
      #pragma unroll
      for (int ss = 0; ss < 3; ++ss)
        while (__hip_atomic_load(&flags[(layer - 1) * 3 + ss], __ATOMIC_RELAXED, __HIP_MEMORY_SCOPE_AGENT) < t + 1)
          __builtin_amdgcn_s_sleep(1);
    }
    if (t > 0) {
      #pragma unroll
      for (int ss = 0; ss < 3; ++ss)
        while (__hip_atomic_load(&flags[layer * 3 + ss], __ATOMIC_RELAXED, __HIP_MEMORY_SCOPE_AGENT) < t)
          __builtin_amdgcn_s_sleep(1);
    }
    __builtin_amdgcn_fence(__ATOMIC_ACQUIRE, "agent");

    // ---- load A-fragments ----
    s16x8 xf[6], hf[6];
    if (layer > 0) {
      const short* src = frag + (size_t)((layer - 1) * 64 + slot) * 6 * 512 + lane * 8;
      #pragma unroll
      for (int kt = 0; kt < 6; ++kt) xf[kt] = *(const s16x8*)(src + kt * 512);
    } else {
      #pragma unroll
      for (int kt = 0; kt < 6; ++kt) xf[kt] = (s16x8){0,0,0,0,0,0,0,0};
    }
    if (t > 0) {
      const short* src = frag + (size_t)(layer * 64 + slot1) * 6 * 512 + lane * 8;
      #pragma unroll
      for (int kt = 0; kt < 6; ++kt) hf[kt] = *(const s16x8*)(src + kt * 512);
    } else {
      #pragma unroll
      for (int kt = 0; kt < 6; ++kt) hf[kt] = (s16x8){0,0,0,0,0,0,0,0};
    }
    if (tid == 0)
      __hip_atomic_store(&prog[blk], t + 1, __ATOMIC_RELEASE, __HIP_MEMORY_SCOPE_AGENT);

    // ---- MFMA: gi += x @ Wih^T ; gh += h @ Whh^T ----
    #pragma unroll
    for (int kt = 0; kt < 6; ++kt) {
      if (layer > 0) {
        agi0 = __builtin_amdgcn_mfma_f32_16x16x32_bf16(xf[kt], WI[0][kt], agi0, 0, 0, 0);
        agi1 = __builtin_amdgcn_mfma_f32_16x16x32_bf16(xf[kt], WI[1][kt], agi1, 0, 0, 0);
        agi2 = __builtin_amdgcn_mfma_f32_16x16x32_bf16(xf[kt], WI[2][kt], agi2, 0, 0, 0);
      }
      agh0 = __builtin_amdgcn_mfma_f32_16x16x32_bf16(hf[kt], WH[0][kt], agh0, 0, 0, 0);
      agh1 = __builtin_amdgcn_mfma_f32_16x16x32_bf16(hf[kt], WH[1][kt], agh1, 0, 0, 0);
      agh2 = __builtin_amdgcn_mfma_f32_16x16x32_bf16(hf[kt], WH[2][kt], agh2, 0, 0, 0);
    }

    // ---- gates (f32, D layout: b = 4*lg + j, unit = u0 + l15) ----
    #pragma unroll
    for (int j = 0; j < 4; ++j) {
      float r = sigm(agi0[j] + agh0[j]);
      float z = sigm(agi1[j] + agh1[j]);
      float n = tanhx(agi2[j] + r * agh2[j]);
      h[j] = n + z * (h[j] - n);
    }

    // ---- publish h' as bf16 A-fragments via LDS transpose ----
    {
      const int e_ = (l15 & 3) + ((w & 1) << 2);
      const int gp = l15 >> 2;
      const int base = (w >> 1) << 9;
      #pragma unroll
      for (int r0 = 0; r0 < 4; ++r0) {
        int b_ = lg * 4 + r0;
        hlds[base + ((b_ | (gp << 4)) << 3) + e_] = f2bf(h[r0]);
      }
    }
    if (layer == 2) {
      #pragma unroll
      for (int r0 = 0; r0 < 4; ++r0) {
        float p = ow * h[r0];
        p += __shfl_xor(p, 1); p += __shfl_xor(p, 2);
        p += __shfl_xor(p, 4); p += __shfl_xor(p, 8);
        if (l15 == 0) plds[w][lg * 4 + r0] = p;
      }
    }
    __syncthreads();
    {
      short* gdst = frag + ((size_t)(layer * 64 + slot) * 6 + sl * 2) * 512;
      ((uint2*)gdst)[tid] = ((const uint2*)hlds)[tid];
    }
    if (layer == 2 && tid < 16) {
      float sm = plds[0][tid] + plds[1][tid] + plds[2][tid] + plds[3][tid];
      part[(size_t)(sl * 16 + tid) * S_ + t] = sm;
    }
    __syncthreads();
    if (tid == 0) {
      __builtin_amdgcn_fence(__ATOMIC_RELEASE, "agent");
      __hip_atomic_store(&flags[blk], t + 1, __ATOMIC_RELAXED, __HIP_MEMORY_SCOPE_AGENT);
    }
  }
}

// ---------------------------------------------------------------------------
// K5: output head: sum partials + out_b, noise mix, clip, tanh gain
// ---------------------------------------------------------------------------
__global__ void k_final(char* ws, const float* __restrict__ noise,
                        const float* __restrict__ outb, const float* __restrict__ lgain,
                        float* __restrict__ out) {
  int i = blockIdx.x * 256 + threadIdx.x;
  if (i >= B_ * S_) return;
  int b = i / S_, s = i - b * S_;
  const float* part = (const float*)(ws + OFF_PART);
  const float* vp   = (const float*)(ws + OFF_V);
  float smp = part[(size_t)(0 + b) * S_ + s] + part[(size_t)(16 + b) * S_ + s]
            + part[(size_t)(32 + b) * S_ + s] + outb[0];
  float v = vp[b * 50 + s / 160];
  float noisy = 0.6f * smp + 0.4f * (noise[(size_t)b * S_ + s] * 0.003f);
  float sm2 = v * smp + (1.f - v) * noisy;
  float wave = fminf(fmaxf(sm2, -1.f), 1.f);
  float gain = fminf(fmaxf(expf(lgain[0]), 0.5f), 1.5f);
  out[i] = 1.1f * tanhf(0.9f * gain * wave);
}

// ---------------------------------------------------------------------------
extern "C" void kernel_launch(void* const* d_in, const int* in_sizes, int n_in,
                              void* d_out, int out_size, void* d_ws, size_t ws_size,
                              hipStream_t stream) {
  (void)in_sizes; (void)n_in; (void)out_size; (void)ws_size;
  const float* feats  = (const float*)d_in[0];
  const float* noise  = (const float*)d_in[1];
  const float* pembed = (const float*)d_in[2];
  const float* fpw1   = (const float*)d_in[3];
  const float* fpb1   = (const float*)d_in[4];
  const float* fpw2   = (const float*)d_in[5];
  const float* fpb2   = (const float*)d_in[6];
  const float* outw   = (const float*)d_in[7];
  const float* outb   = (const float*)d_in[8];
  const float* lgain  = (const float*)d_in[9];
  const float* wih0   = (const float*)d_in[10];
  const float* whh0   = (const float*)d_in[11];
  const float* bih0   = (const float*)d_in[12];
  const float* bhh0   = (const float*)d_in[13];
  const float* wih1   = (const float*)d_in[14];
  const float* whh1   = (const float*)d_in[15];
  const float* bih1   = (const float*)d_in[16];
  const float* bhh1   = (const float*)d_in[17];
  const float* wih2   = (const float*)d_in[18];
  const float* whh2   = (const float*)d_in[19];
  const float* bih2   = (const float*)d_in[20];
  const float* bhh2   = (const float*)d_in[21];
  char* ws = (char*)d_ws;
  float* out = (float*)d_out;

  hipMemsetAsync(ws, 0, 1024, stream);                       // flags + prog
  hipLaunchKernelGGL(k_wprep, dim3(1080), dim3(64), 0, stream,
                     whh0, wih1, whh1, wih2, whh2, ws);
  hipLaunchKernelGGL(k_frame, dim3(B_ * T_), dim3(128), 0, stream,
                     feats, pembed, fpw1, fpb1, fpw2, fpb2, ws);
  hipLaunchKernelGGL(k_phase, dim3(B_), dim3(256), 0, stream, ws);
  hipLaunchKernelGGL(k_gbase, dim3(TS_), dim3(256), 0, stream, wih0, bih0, ws);
  hipLaunchKernelGGL(k_gru, dim3(9), dim3(256), 0, stream, ws, wih0,
                     bih0, bhh0, bih1, bhh1, bih2, bhh2, outw);
  hipLaunchKernelGGL(k_final, dim3((B_ * S_ + 255) / 256), dim3(256), 0, stream,
                     ws, noise, outb, lgain, out);
}

// Round 2
// 27465.884 us; speedup vs baseline: 1.1853x; 1.1853x over previous
//
#include <hip/hip_runtime.h>

// ---------------------------------------------------------------------------
// FarGAN wave head: frame MLP + phase gen + 3-layer GRU (pipelined across 9
// persistent workgroups, bf16 MFMA, register-resident weights) + output head.
// R1: replace per-step agent fences (buffer_wbl2/buffer_inv = L2 flush per
// step!) with per-access cache-bypass atomics (sc0 sc1); one counter/layer.
// ---------------------------------------------------------------------------

#define B_    16
#define T_    50
#define SF_   4
#define SPS_  40
#define S_    8000      // T*SF*SPS
#define TS_   200       // T*SF
#define DIN_  48
#define PED_  64
#define COND_ 128
#define GRUD_ 192
#define G3_   576
#define GRUIN_ 194
#define TWO_PI_F 6.2831853071795864769f

// workspace byte offsets (all 256-aligned)
#define OFF_FLAGS 0          // 3 counters, 128B apart: publish count per layer
#define OFF_PROG  512        // 3 counters, 128B apart: consume count per layer
#define OFF_DV    1024       // 16*50 f32
#define OFF_V     8192       // 16*50 f32
#define OFF_SIN   32768      // 8000*16 f32  sin[t][b]
#define OFF_COS   557056     // 8000*16 f32
#define OFF_PE    1081344    // 16*50*64 f32
#define OFF_COND  1310720    // 16*200*128 f32
#define OFF_GB    2949120    // gbase: 200*36*64*4 f32 (D-tile layout)
#define OFF_WF    10321920   // wfrag: 5*36*6*64*8 bf16 (B-frag layout)
#define OFF_FRAG  11427840   // fragbuf: 3*64*6*64*8 bf16 (A-frag ring)
#define OFF_PART  12607488   // part: 3*16*8000 f32
// end ~ 14.14 MB

typedef short s16x8 __attribute__((ext_vector_type(8)));
typedef float f32x4 __attribute__((ext_vector_type(4)));
typedef unsigned long long u64;

__device__ __forceinline__ short f2bf(float f) {
  unsigned u = __float_as_uint(f);
  unsigned r = (u + 0x7FFFu + ((u >> 16) & 1u)) >> 16;   // RNE
  return (short)r;
}
__device__ __forceinline__ float sigm(float x) {
  return __fdividef(1.f, 1.f + __expf(-x));
}
__device__ __forceinline__ float tanhx(float x) {
  float e = __expf(2.f * x);
  return __fdividef(e - 1.f, e + 1.f);
}

// cache-bypassing (agent-coherent) 16B fragment load as 2x u64 atomics
__device__ __forceinline__ s16x8 ld_frag_coh(const short* p) {
  union { u64 u[2]; s16x8 v; } r;
  r.u[0] = __hip_atomic_load((const u64*)p,     __ATOMIC_RELAXED, __HIP_MEMORY_SCOPE_AGENT);
  r.u[1] = __hip_atomic_load((const u64*)p + 1, __ATOMIC_RELAXED, __HIP_MEMORY_SCOPE_AGENT);
  return r.v;
}

// ---------------------------------------------------------------------------
// K1: per-(b,t) frame processing: period/idx/v/delta, pe lookup, 2-layer MLP
// ---------------------------------------------------------------------------
__global__ void k_frame(const float* __restrict__ feats,
                        const float* __restrict__ pembed,
                        const float* __restrict__ w1, const float* __restrict__ b1,
                        const float* __restrict__ w2, const float* __restrict__ b2,
                        char* ws) {
  const int bt = blockIdx.x;            // b*50 + t
  const int tid = threadIdx.x;          // 128 threads
  float* dvp = (float*)(ws + OFF_DV);
  float* vp  = (float*)(ws + OFF_V);
  float* pep = (float*)(ws + OFF_PE);
  float* cnd = (float*)(ws + OFF_COND);

  __shared__ float fin[112];
  __shared__ float h1[256];
  __shared__ int   sidx;

  if (tid == 0) {
    float f0 = feats[bt * 48 + 46];
    float vo = feats[bt * 48 + 47];
    float period = fminf(fmaxf(256.f * exp2f(-(f0 + 2.f)), 32.f), 255.f);
    int idx = (int)rintf(period) - 32;             // jnp.round = RNE
    float f0hz = 16000.f / fmaxf(period, 1.f);
    float v = fminf(fmaxf(vo, 0.f), 1.f);
    float delta = TWO_PI_F * fmaxf(f0hz, 60.f) * (1.f / 16000.f);
    dvp[bt] = delta * v;
    vp[bt] = v;
    sidx = idx;
  }
  __syncthreads();
  if (tid < 48) fin[tid] = feats[bt * 48 + tid];
  if (tid < 64) {
    float pv = pembed[sidx * 64 + tid];
    fin[48 + tid] = pv;
    pep[bt * 64 + tid] = pv;
  }
  __syncthreads();
  #pragma unroll
  for (int rr = 0; rr < 2; ++rr) {
    int r = tid + rr * 128;
    const float* wr = w1 + r * 112;
    float acc = b1[r];
    #pragma unroll 4
    for (int k = 0; k < 112; ++k) acc += wr[k] * fin[k];
    // exact gelu
    h1[r] = 0.5f * acc * (1.f + erff(acc * 0.70710678118654752440f));
  }
  __syncthreads();
  const int b = bt / 50, t = bt - b * 50;
  #pragma unroll
  for (int rr = 0; rr < 4; ++rr) {
    int r = tid + rr * 128;
    const float* wr = w2 + r * 256;
    float acc = b2[r];
    #pragma unroll 4
    for (int k = 0; k < 256; ++k) acc += wr[k] * h1[k];
    int sf = r >> 7, c = r & 127;
    cnd[((b * 200) + (t * 4 + sf)) * 128 + c] = acc;
  }
}

// ---------------------------------------------------------------------------
// K2: phase cumsum + sin/cos tables  (one block per batch element)
// ---------------------------------------------------------------------------
__global__ void k_phase(char* ws) {
  const int b = blockIdx.x;
  const int tid = threadIdx.x;          // 256
  const float* dvp = (const float*)(ws + OFF_DV);
  float* sinA = (float*)(ws + OFF_SIN);
  float* cosA = (float*)(ws + OFF_COS);

  __shared__ float ps[200];
  __shared__ float dvs[200];
  if (tid == 0) {
    float c = 0.f;
    for (int ts = 0; ts < 200; ++ts) {
      float d = dvp[b * 50 + (ts >> 2)];
      dvs[ts] = d;
      float inc = d * (float)SPS_;
      c = c + inc;                        // inclusive cumsum (match ref order)
      ps[ts] = fmodf(c - inc, TWO_PI_F);
    }
  }
  __syncthreads();
  for (int i = tid; i < S_; i += 256) {
    int ts = i / 40, k = i - ts * 40;
    float ph = ps[ts] + dvs[ts] * (float)k;
    sinA[(size_t)i * 16 + b] = sinf(ph);
    cosA[(size_t)i * 16 + b] = cosf(ph);
  }
}

// ---------------------------------------------------------------------------
// K3: gbase[ts][nt][lane][j] = b_ih0 + Wc@cond + Wp@pe, in MFMA D-tile layout
// ---------------------------------------------------------------------------
__global__ void k_gbase(const float* __restrict__ wih0,
                        const float* __restrict__ bih0, char* ws) {
  const int ts = blockIdx.x;            // 200 blocks, 256 threads
  const int t = ts >> 2;
  const int tid = threadIdx.x;
  const float* cnd = (const float*)(ws + OFF_COND);
  const float* pep = (const float*)(ws + OFF_PE);
  float* gbp = (float*)(ws + OFF_GB);

  __shared__ float c_s[16][128];
  __shared__ float p_s[16][64];
  for (int i = tid; i < 2048; i += 256) c_s[i >> 7][i & 127] = cnd[((i >> 7) * 200 + ts) * 128 + (i & 127)];
  for (int i = tid; i < 1024; i += 256) p_s[i >> 6][i & 63] = pep[((i >> 6) * 50 + t) * 64 + (i & 63)];
  __syncthreads();

  for (int i = tid; i < 9216; i += 256) {
    int row = i >> 4, b = i & 15;
    const float* wr = wih0 + (size_t)row * GRUIN_;
    float acc = bih0[row];
    #pragma unroll 4
    for (int k = 0; k < 128; ++k) acc += wr[k] * c_s[b][k];
    #pragma unroll 4
    for (int k = 0; k < 64; ++k) acc += wr[128 + k] * p_s[b][k];
    int nt = row >> 4, l15 = row & 15;
    int lane = l15 | ((b >> 2) << 4), j = b & 3;
    gbp[((size_t)(ts * 36 + nt) * 64 + lane) * 4 + j] = acc;
  }
}

// ---------------------------------------------------------------------------
// K_w: pack the 5 recurrent weight matrices (576x192) into bf16 B-fragments.
// k-map: k = kt*32 + 16*(e>>2) + 4*(lane>>4) + (e&3)  (same map used when
// packing A-fragments at publish time -> consistent regardless of HW k order)
// ---------------------------------------------------------------------------
__global__ void k_wprep(const float* __restrict__ whh0, const float* __restrict__ wih1,
                        const float* __restrict__ whh1, const float* __restrict__ wih2,
                        const float* __restrict__ whh2, char* ws) {
  const int blk = blockIdx.x;           // 5*36*6 = 1080 blocks, 64 threads
  const int mat = blk / 216, rem = blk - mat * 216;
  const int nt = rem / 6, kt = rem - nt * 6;
  const int lane = threadIdx.x;
  const float* W = (mat == 0) ? whh0 : (mat == 1) ? wih1 : (mat == 2) ? whh1
                  : (mat == 3) ? wih2 : whh2;
  short* dst = (short*)(ws + OFF_WF) + ((size_t)(mat * 36 + nt) * 6 + kt) * 512 + lane * 8;
  const int row = nt * 16 + (lane & 15);
  const int g = lane >> 4;
  #pragma unroll
  for (int e = 0; e < 8; ++e) {
    int k = kt * 32 + 16 * (e >> 2) + 4 * g + (e & 3);
    dst[e] = f2bf(W[(size_t)row * 192 + k]);
  }
}

// ---------------------------------------------------------------------------
// K4: persistent pipelined GRU. 9 blocks = 3 layers x 3 unit-slices.
// Each block: 256 threads = 4 waves; wave w owns 16 GRU units; weights live
// in VGPRs as bf16 MFMA fragments; h handoff via coherent (sc0 sc1) atomics.
// ---------------------------------------------------------------------------
__global__ __launch_bounds__(256, 1)
void k_gru(char* ws, const float* __restrict__ wih0,
           const float* __restrict__ bih0, const float* __restrict__ bhh0,
           const float* __restrict__ bih1, const float* __restrict__ bhh1,
           const float* __restrict__ bih2, const float* __restrict__ bhh2,
           const float* __restrict__ outw) {
  const int blk = blockIdx.x;
  const int layer = blk / 3, sl = blk - layer * 3;
  const int tid = threadIdx.x;
  const int w = tid >> 6, lane = tid & 63, lg = lane >> 4, l15 = lane & 15;

  int* cnt  = (int*)(ws + OFF_FLAGS);   // cnt[layer*32], 128B apart
  int* prog = (int*)(ws + OFF_PROG);    // prog[layer*32]
  const float* sinA = (const float*)(ws + OFF_SIN);
  const float* cosA = (const float*)(ws + OFF_COS);
  const float* gbp  = (const float*)(ws + OFF_GB);
  const short* wf   = (const short*)(ws + OFF_WF);
  short* frag       = (short*)(ws + OFF_FRAG);
  float* part       = (float*)(ws + OFF_PART);

  __shared__ __align__(16) short hlds[1024];   // 2 ktiles x 64 lanes x 8
  __shared__ float plds[4][16];

  const int u0 = sl * 64 + w * 16;
  const int ntb = sl * 4 + w;
  const int nts[3] = {ntb, 12 + ntb, 24 + ntb};
  const int rowR = u0 + l15, rowZ = 192 + rowR, rowN = 384 + rowR;

  const float* bih; const float* bhh; int matIH, matHH;
  if (layer == 0)      { bih = bih0; bhh = bhh0; matIH = 0; matHH = 0; }
  else if (layer == 1) { bih = bih1; bhh = bhh1; matIH = 1; matHH = 2; }
  else                 { bih = bih2; bhh = bhh2; matIH = 3; matHH = 4; }

  const float bgi0 = bih[rowR], bgi1 = bih[rowZ], bgi2 = bih[rowN];
  const float bgh0 = bhh[rowR], bgh1 = bhh[rowZ], bgh2 = bhh[rowN];

  // register-resident weight fragments
  s16x8 WH[3][6], WI[3][6];
  #pragma unroll
  for (int g = 0; g < 3; ++g) {
    #pragma unroll
    for (int kt = 0; kt < 6; ++kt) {
      WH[g][kt] = *(const s16x8*)(wf + ((size_t)(matHH * 36 + nts[g]) * 6 + kt) * 512 + lane * 8);
      if (layer > 0)
        WI[g][kt] = *(const s16x8*)(wf + ((size_t)(matIH * 36 + nts[g]) * 6 + kt) * 512 + lane * 8);
      else
        WI[g][kt] = (s16x8){0,0,0,0,0,0,0,0};
    }
  }
  float wsn[3] = {0.f,0.f,0.f}, wcs[3] = {0.f,0.f,0.f};
  if (layer == 0) {
    const int rows[3] = {rowR, rowZ, rowN};
    #pragma unroll
    for (int g = 0; g < 3; ++g) {
      wsn[g] = wih0[(size_t)rows[g] * GRUIN_ + 192];
      wcs[g] = wih0[(size_t)rows[g] * GRUIN_ + 193];
    }
  }
  const float ow = (layer == 2) ? outw[u0 + l15] : 0.f;

  f32x4 h = {0.f, 0.f, 0.f, 0.f};
  f32x4 gbr[3]; gbr[0] = h; gbr[1] = h; gbr[2] = h;

  for (int t = 0; t < S_; ++t) {
    const int slot = t & 63, slot1 = (t - 1) & 63;

    // ---- gi base (no flag dependency -> do before spins) ----
    f32x4 agi0, agi1, agi2;
    f32x4 agh0 = {bgh0, bgh0, bgh0, bgh0};
    f32x4 agh1 = {bgh1, bgh1, bgh1, bgh1};
    f32x4 agh2 = {bgh2, bgh2, bgh2, bgh2};
    if (layer == 0) {
      if ((t % SPS_) == 0) {
        int ts = t / SPS_;
        #pragma unroll
        for (int g = 0; g < 3; ++g)
          gbr[g] = *(const f32x4*)(gbp + ((size_t)(ts * 36 + nts[g]) * 64 + lane) * 4);
      }
      f32x4 s4 = *(const f32x4*)(sinA + (size_t)t * 16 + lg * 4);
      f32x4 c4 = *(const f32x4*)(cosA + (size_t)t * 16 + lg * 4);
      agi0 = gbr[0] + s4 * wsn[0] + c4 * wcs[0];
      agi1 = gbr[1] + s4 * wsn[1] + c4 * wcs[1];
      agi2 = gbr[2] + s4 * wsn[2] + c4 * wcs[2];
    } else {
      agi0 = (f32x4){bgi0, bgi0, bgi0, bgi0};
      agi1 = (f32x4){bgi1, bgi1, bgi1, bgi1};
      agi2 = (f32x4){bgi2, bgi2, bgi2, bgi2};
    }

    // ---- coarse back-pressure (ring is 64 slots; keep lead < ~40) ----
    if ((t & 15) == 0 && t >= 48) {
      int need = 3 * (t - 40);
      while (__hip_atomic_load(&prog[layer * 32], __ATOMIC_RELAXED, __HIP_MEMORY_SCOPE_AGENT) < need)
        __builtin_amdgcn_s_sleep(2);
      if (layer < 2)
        while (__hip_atomic_load(&prog[(layer + 1) * 32], __ATOMIC_RELAXED, __HIP_MEMORY_SCOPE_AGENT) < need)
          __builtin_amdgcn_s_sleep(2);
    }

    // ---- spin on producer counters (no cache maintenance, bypass loads) ----
    if (layer > 0) {
      const int tgt = 3 * (t + 1);
      while (__hip_atomic_load(&cnt[(layer - 1) * 32], __ATOMIC_RELAXED, __HIP_MEMORY_SCOPE_AGENT) < tgt) {}
    }
    if (t > 0) {
      const int tgt = 3 * t;
      while (__hip_atomic_load(&cnt[layer * 32], __ATOMIC_RELAXED, __HIP_MEMORY_SCOPE_AGENT) < tgt) {}
    }
    __builtin_amdgcn_fence(__ATOMIC_ACQUIRE, "workgroup");  // compiler ordering only

    // ---- load A-fragments (coherent bypass loads) ----
    s16x8 xf[6], hf[6];
    if (layer > 0) {
      const short* src = frag + (size_t)((layer - 1) * 64 + slot) * 6 * 512 + lane * 8;
      #pragma unroll
      for (int kt = 0; kt < 6; ++kt) xf[kt] = ld_frag_coh(src + kt * 512);
    } else {
      #pragma unroll
      for (int kt = 0; kt < 6; ++kt) xf[kt] = (s16x8){0,0,0,0,0,0,0,0};
    }
    if (t > 0) {
      const short* src = frag + (size_t)(layer * 64 + slot1) * 6 * 512 + lane * 8;
      #pragma unroll
      for (int kt = 0; kt < 6; ++kt) hf[kt] = ld_frag_coh(src + kt * 512);
    } else {
      #pragma unroll
      for (int kt = 0; kt < 6; ++kt) hf[kt] = (s16x8){0,0,0,0,0,0,0,0};
    }
    if (tid == 0)
      __hip_atomic_fetch_add(&prog[layer * 32], 1, __ATOMIC_RELAXED, __HIP_MEMORY_SCOPE_AGENT);

    // ---- MFMA: gi += x @ Wih^T ; gh += h @ Whh^T ----
    #pragma unroll
    for (int kt = 0; kt < 6; ++kt) {
      if (layer > 0) {
        agi0 = __builtin_amdgcn_mfma_f32_16x16x32_bf16(xf[kt], WI[0][kt], agi0, 0, 0, 0);
        agi1 = __builtin_amdgcn_mfma_f32_16x16x32_bf16(xf[kt], WI[1][kt], agi1, 0, 0, 0);
        agi2 = __builtin_amdgcn_mfma_f32_16x16x32_bf16(xf[kt], WI[2][kt], agi2, 0, 0, 0);
      }
      agh0 = __builtin_amdgcn_mfma_f32_16x16x32_bf16(hf[kt], WH[0][kt], agh0, 0, 0, 0);
      agh1 = __builtin_amdgcn_mfma_f32_16x16x32_bf16(hf[kt], WH[1][kt], agh1, 0, 0, 0);
      agh2 = __builtin_amdgcn_mfma_f32_16x16x32_bf16(hf[kt], WH[2][kt], agh2, 0, 0, 0);
    }

    // ---- gates (f32, D layout: b = 4*lg + j, unit = u0 + l15) ----
    #pragma unroll
    for (int j = 0; j < 4; ++j) {
      float r = sigm(agi0[j] + agh0[j]);
      float z = sigm(agi1[j] + agh1[j]);
      float n = tanhx(agi2[j] + r * agh2[j]);
      h[j] = n + z * (h[j] - n);
    }

    // ---- publish h' as bf16 A-fragments via LDS transpose ----
    {
      const int e_ = (l15 & 3) + ((w & 1) << 2);
      const int gp = l15 >> 2;
      const int base = (w >> 1) << 9;
      #pragma unroll
      for (int r0 = 0; r0 < 4; ++r0) {
        int b_ = lg * 4 + r0;
        hlds[base + ((b_ | (gp << 4)) << 3) + e_] = f2bf(h[r0]);
      }
    }
    if (layer == 2) {
      #pragma unroll
      for (int r0 = 0; r0 < 4; ++r0) {
        float p = ow * h[r0];
        p += __shfl_xor(p, 1); p += __shfl_xor(p, 2);
        p += __shfl_xor(p, 4); p += __shfl_xor(p, 8);
        if (l15 == 0) plds[w][lg * 4 + r0] = p;
      }
    }
    __syncthreads();
    {
      short* gdst = frag + ((size_t)(layer * 64 + slot) * 6 + sl * 2) * 512;
      u64 v = ((const u64*)hlds)[tid];
      __hip_atomic_store((u64*)gdst + tid, v, __ATOMIC_RELAXED, __HIP_MEMORY_SCOPE_AGENT);
    }
    if (layer == 2 && tid < 16) {
      float sm = plds[0][tid] + plds[1][tid] + plds[2][tid] + plds[3][tid];
      part[(size_t)(sl * 16 + tid) * S_ + t] = sm;
    }
    __syncthreads();   // drains each thread's vmcnt (incl. the data stores)
    if (tid == 0) {
      __builtin_amdgcn_fence(__ATOMIC_RELEASE, "workgroup");  // compiler ordering only
      __hip_atomic_fetch_add(&cnt[layer * 32], 1, __ATOMIC_RELAXED, __HIP_MEMORY_SCOPE_AGENT);
    }
  }
}

// ---------------------------------------------------------------------------
// K5: output head: sum partials + out_b, noise mix, clip, tanh gain
// ---------------------------------------------------------------------------
__global__ void k_final(char* ws, const float* __restrict__ noise,
                        const float* __restrict__ outb, const float* __restrict__ lgain,
                        float* __restrict__ out) {
  int i = blockIdx.x * 256 + threadIdx.x;
  if (i >= B_ * S_) return;
  int b = i / S_, s = i - b * S_;
  const float* part = (const float*)(ws + OFF_PART);
  const float* vp   = (const float*)(ws + OFF_V);
  float smp = part[(size_t)(0 + b) * S_ + s] + part[(size_t)(16 + b) * S_ + s]
            + part[(size_t)(32 + b) * S_ + s] + outb[0];
  float v = vp[b * 50 + s / 160];
  float noisy = 0.6f * smp + 0.4f * (noise[(size_t)b * S_ + s] * 0.003f);
  float sm2 = v * smp + (1.f - v) * noisy;
  float wave = fminf(fmaxf(sm2, -1.f), 1.f);
  float gain = fminf(fmaxf(expf(lgain[0]), 0.5f), 1.5f);
  out[i] = 1.1f * tanhf(0.9f * gain * wave);
}

// ---------------------------------------------------------------------------
extern "C" void kernel_launch(void* const* d_in, const int* in_sizes, int n_in,
                              void* d_out, int out_size, void* d_ws, size_t ws_size,
                              hipStream_t stream) {
  (void)in_sizes; (void)n_in; (void)out_size; (void)ws_size;
  const float* feats  = (const float*)d_in[0];
  const float* noise  = (const float*)d_in[1];
  const float* pembed = (const float*)d_in[2];
  const float* fpw1   = (const float*)d_in[3];
  const float* fpb1   = (const float*)d_in[4];
  const float* fpw2   = (const float*)d_in[5];
  const float* fpb2   = (const float*)d_in[6];
  const float* outw   = (const float*)d_in[7];
  const float* outb   = (const float*)d_in[8];
  const float* lgain  = (const float*)d_in[9];
  const float* wih0   = (const float*)d_in[10];
  const float* whh0   = (const float*)d_in[11];
  const float* bih0   = (const float*)d_in[12];
  const float* bhh0   = (const float*)d_in[13];
  const float* wih1   = (const float*)d_in[14];
  const float* whh1   = (const float*)d_in[15];
  const float* bih1   = (const float*)d_in[16];
  const float* bhh1   = (const float*)d_in[17];
  const float* wih2   = (const float*)d_in[18];
  const float* whh2   = (const float*)d_in[19];
  const float* bih2   = (const float*)d_in[20];
  const float* bhh2   = (const float*)d_in[21];
  char* ws = (char*)d_ws;
  float* out = (float*)d_out;

  hipMemsetAsync(ws, 0, 1024, stream);                       // cnt + prog
  hipLaunchKernelGGL(k_wprep, dim3(1080), dim3(64), 0, stream,
                     whh0, wih1, whh1, wih2, whh2, ws);
  hipLaunchKernelGGL(k_frame, dim3(B_ * T_), dim3(128), 0, stream,
                     feats, pembed, fpw1, fpb1, fpw2, fpb2, ws);
  hipLaunchKernelGGL(k_phase, dim3(B_), dim3(256), 0, stream, ws);
  hipLaunchKernelGGL(k_gbase, dim3(TS_), dim3(256), 0, stream, wih0, bih0, ws);
  hipLaunchKernelGGL(k_gru, dim3(9), dim3(256), 0, stream, ws, wih0,
                     bih0, bhh0, bih1, bhh1, bih2, bhh2, outw);
  hipLaunchKernelGGL(k_final, dim3((B_ * S_ + 255) / 256), dim3(256), 0, stream,
                     ws, noise, outb, lgain, out);
}